// Round 5
// baseline (425.651 us; speedup 1.0000x reference)
//
#include <hip/hip_runtime.h>

typedef short bf16x8 __attribute__((ext_vector_type(8)));
typedef float f32x4 __attribute__((ext_vector_type(4)));

__device__ __forceinline__ unsigned short f2bf(float f) {
  unsigned x = __float_as_uint(f);
  return (unsigned short)((x + 0x7fffu + ((x >> 16) & 1u)) >> 16);  // RNE
}

// pack two fp32 -> one dword of two RNE bf16 (lo in low short)
__device__ __forceinline__ unsigned pack2bf(float lo, float hi) {
  unsigned a = __float_as_uint(lo), b = __float_as_uint(hi);
  a = a + 0x7fffu + ((a >> 16) & 1u);
  b = b + 0x7fffu + ((b >> 16) & 1u);
  return __builtin_amdgcn_perm(b, a, 0x07060302u);  // [b.hi16, a.hi16]
}

// x fp32 -> bf16, 8 elems/thread
__global__ __launch_bounds__(256)
void cvt_bf16(const float* __restrict__ in, unsigned short* __restrict__ out) {
  int i = (blockIdx.x * 256 + threadIdx.x) * 8;
  float4 v0 = *(const float4*)(in + i);
  float4 v1 = *(const float4*)(in + i + 4);
  uint4 o = { pack2bf(v0.x, v0.y), pack2bf(v0.z, v0.w),
              pack2bf(v1.x, v1.y), pack2bf(v1.z, v1.w) };
  *(uint4*)(out + i) = o;
}

// A [M x K] bf16 row-major, W [K x N] fp32 row-major (pk-converted in staging).
// Block tile BM=128, BN=64, BK=64; 256 thr = 4 waves 2x2 (64x32 each).
// Mask: N-col-block sj (width CW) live for K in [0, (sj+1)*KROW).
// Split-K: z-th of KS slices of the live BK-iters; each z writes its own
// fp32 partial at out + z*256*N (plain stores; empty slices write nothing,
// combine kernels recompute liveness analytically).
template<int KROW, int CW, int KS>
__global__ __launch_bounds__(256, 4)
void gemm_sk(const unsigned short* __restrict__ A, const float* __restrict__ W,
             float* __restrict__ out, int K, int N)
{
  __shared__ unsigned short Xs[128 * 72];  // [m][k], +8 pad
  __shared__ unsigned int   Wt[64 * 32];   // [n][kpair], XOR-group-swizzled

  const int n0 = blockIdx.x * 64;
  const int m0 = blockIdx.y * 128;
  const int nIter = ((n0 / CW) + 1) * (KROW / 64);
  const int i0 = ((int)blockIdx.z) * nIter / KS;
  const int i1 = ((int)blockIdx.z + 1) * nIter / KS;
  if (i0 == i1) return;                    // uniform exit, before any barrier
  const int kbeg = i0 * 64, kend = i1 * 64;

  const int tid  = threadIdx.x;
  const int lane = tid & 63, wave = tid >> 6;
  const int l15  = lane & 15, quad = lane >> 4;
  const int wm0  = (wave & 1) * 64, wn0 = (wave >> 1) * 32;

  const int cg = tid & 7;    // 8-elem column group
  const int rw = tid >> 3;   // A row 0..31 / W k-pair 0..31

  int4   av[4];              // A: 4 rows x 8 bf16
  float4 wv[2][2];           // W: 2 adjacent k-rows x 8 fp32

  auto loadG = [&](int kt) {
    const unsigned short* ap = A + (size_t)(m0 + rw) * K + kt + cg * 8;
#pragma unroll
    for (int i = 0; i < 4; ++i)
      av[i] = *(const int4*)(ap + (size_t)i * 32 * K);
    const float* wp = W + (size_t)(kt + rw * 2) * N + n0 + cg * 8;
    wv[0][0] = *(const float4*)wp;
    wv[0][1] = *(const float4*)(wp + 4);
    wv[1][0] = *(const float4*)(wp + N);
    wv[1][1] = *(const float4*)(wp + N + 4);
  };

  auto storeLDS = [&]() {
#pragma unroll
    for (int i = 0; i < 4; ++i)
      *(int4*)(&Xs[(rw + i * 32) * 72 + cg * 8]) = av[i];
    const float* f0 = (const float*)&wv[0][0];  // k row 2rw   (8 n's)
    const float* f1 = (const float*)&wv[1][0];  // k row 2rw+1
    const int gi = rw >> 2, lc = rw & 3;
#pragma unroll
    for (int j = 0; j < 8; ++j) {
      unsigned d = pack2bf(f0[j], f1[j]);      // (k, k+1) bf16 pair
      const int gsw = gi ^ j ^ cg;             // n_l = cg*8+j: ^(n&7)^(n>>3)
      Wt[(cg * 8 + j) * 32 + gsw * 4 + lc] = d;
    }
  };

  f32x4 acc[4][2];
#pragma unroll
  for (int mi = 0; mi < 4; ++mi)
#pragma unroll
    for (int ni = 0; ni < 2; ++ni)
      acc[mi][ni] = (f32x4){0.f, 0.f, 0.f, 0.f};

  loadG(kbeg);
  for (int kt = kbeg; kt < kend; kt += 64) {
    __syncthreads();                        // prior tile's LDS reads done
    storeLDS();
    if (kt + 64 < kend) loadG(kt + 64);     // prefetch overlaps barrier+MFMA
    __syncthreads();                        // stores visible
#pragma unroll
    for (int kk = 0; kk < 64; kk += 32) {
      bf16x8 af[4], bf[2];
#pragma unroll
      for (int mi = 0; mi < 4; ++mi)
        af[mi] = *(const bf16x8*)(&Xs[(wm0 + mi * 16 + l15) * 72 + kk + quad * 8]);
#pragma unroll
      for (int ni = 0; ni < 2; ++ni) {
        const int n_l = wn0 + ni * 16 + l15;
        const int gsw = ((kk >> 3) + quad) ^ (n_l & 7) ^ (n_l >> 3);
        bf[ni] = *(const bf16x8*)(&Wt[n_l * 32 + gsw * 4]);
      }
#pragma unroll
      for (int mi = 0; mi < 4; ++mi)
#pragma unroll
        for (int ni = 0; ni < 2; ++ni)
          acc[mi][ni] = __builtin_amdgcn_mfma_f32_16x16x32_bf16(
              af[mi], bf[ni], acc[mi][ni], 0, 0, 0);
    }
  }

  // epilogue: C/D layout col=lane&15, row=quad*4+reg; plain stores to partial
  float* po = out + (size_t)blockIdx.z * 256 * N;
#pragma unroll
  for (int mi = 0; mi < 4; ++mi) {
#pragma unroll
    for (int ni = 0; ni < 2; ++ni) {
      const int n_out = n0 + wn0 + ni * 16 + l15;
#pragma unroll
      for (int r = 0; r < 4; ++r) {
        const int m_out = m0 + wm0 + mi * 16 + quad * 4 + r;
        po[(size_t)m_out * N + n_out] = acc[mi][ni][r];
      }
    }
  }
}

// Hb = bf16(relu(sum_z live P1[z] + b1));  N=8192, CW=128, KS=4
__global__ __launch_bounds__(256)
void combine1(const float* __restrict__ P, const float* __restrict__ b,
              unsigned short* __restrict__ out) {
  int i = (blockIdx.x * 256 + threadIdx.x) * 4;
  const int n = i & 8191;
  const int nIter = (n >> 7) + 1;
  float4 s = {0.f, 0.f, 0.f, 0.f};
#pragma unroll
  for (int z = 0; z < 4; ++z) {
    if (((z + 1) * nIter) / 4 > (z * nIter) / 4) {
      float4 v = *(const float4*)(P + (size_t)z * 2097152 + i);
      s.x += v.x; s.y += v.y; s.z += v.z; s.w += v.w;
    }
  }
  float4 bv = *(const float4*)(b + n);
  s.x = fmaxf(s.x + bv.x, 0.f);
  s.y = fmaxf(s.y + bv.y, 0.f);
  s.z = fmaxf(s.z + bv.z, 0.f);
  s.w = fmaxf(s.w + bv.w, 0.f);
  uint2 o = { pack2bf(s.x, s.y), pack2bf(s.z, s.w) };
  *(uint2*)(out + i) = o;
}

// out = sum_z live P2[z] + b2;  N=4096, CW=64, KROW=128 -> nIter=(sj+1)*2, KS=8
__global__ __launch_bounds__(256)
void combine2(const float* __restrict__ P, const float* __restrict__ b,
              float* __restrict__ out) {
  int i = (blockIdx.x * 256 + threadIdx.x) * 4;
  const int n = i & 4095;
  const int nIter = ((n >> 6) + 1) * 2;
  float4 s = {0.f, 0.f, 0.f, 0.f};
#pragma unroll
  for (int z = 0; z < 8; ++z) {
    if (((z + 1) * nIter) / 8 > (z * nIter) / 8) {
      float4 v = *(const float4*)(P + (size_t)z * 1048576 + i);
      s.x += v.x; s.y += v.y; s.z += v.z; s.w += v.w;
    }
  }
  float4 bv = *(const float4*)(b + n);
  s.x += bv.x; s.y += bv.y; s.z += bv.z; s.w += bv.w;
  *(float4*)(out + i) = s;
}

extern "C" void kernel_launch(void* const* d_in, const int* in_sizes, int n_in,
                              void* d_out, int out_size, void* d_ws, size_t ws_size,
                              hipStream_t stream) {
  const float* x  = (const float*)d_in[0];  // [256,64,64] fp32
  const float* W1 = (const float*)d_in[1];  // [4096,8192] fp32
  const float* b1 = (const float*)d_in[2];  // [8192] fp32
  const float* W2 = (const float*)d_in[3];  // [8192,4096] fp32
  const float* b2 = (const float*)d_in[4];  // [4096] fp32
  // dims hardcoded: B=256, S=64, I=64, H=128, O=64

  char* ws = (char*)d_ws;
  unsigned short* xb = (unsigned short*)ws;                     // 2 MB bf16
  unsigned short* Hb = (unsigned short*)(ws + 2097152ull * 1);  // 4 MB bf16
  float* P1 = (float*)(ws + 6291456ull);                        // 4 x 8 MB fp32
  float* P2 = (float*)(ws + 39845888ull);                       // 8 x 4 MB fp32
  float* out = (float*)d_out;                                   // [256,4096] fp32

  // x fp32 -> bf16 (1M elems, 8/thread)
  cvt_bf16<<<dim3(512), 256, 0, stream>>>(x, xb);

  // GEMM1: xb @ W1, mask 64(K) x 128(N), split-K x4 -> P1
  gemm_sk<64, 128, 4><<<dim3(128, 2, 4), 256, 0, stream>>>(
      xb, W1, P1, 4096, 8192);

  // Hb = bf16(relu(sum P1 + b1)), 2M elems
  combine1<<<dim3(2048), 256, 0, stream>>>(P1, b1, Hb);

  // GEMM2: Hb @ W2, mask 128(K) x 64(N), split-K x8 -> P2
  gemm_sk<128, 64, 8><<<dim3(64, 2, 8), 256, 0, stream>>>(
      Hb, W2, P2, 8192, 4096);

  // out = sum P2 + b2, 1M elems
  combine2<<<dim3(1024), 256, 0, stream>>>(P2, b2, out);
}